// Round 12
// baseline (308.722 us; speedup 1.0000x reference)
//
#include <hip/hip_runtime.h>
#include <math.h>

#define NV 8192
#define NE 4096
#define DIN 512
#define DH 256
#define CAP_E 96
#define CAP_V 64
#define NPROJ (NV / 32)      // 256 proj-GEMM blocks
#define NCOL  (NE / 32)      // 128 column-scan blocks (32 edges = 128B strip each)
#define NROW  (NV / 4)       // 2048 row-scan blocks (4 full-row waves each)

// ---------------- workspace layout (float offsets) ----------------
#define OFF_XH   0                       // V*DH fp32 (residual)
#define OFF_UB   (OFF_XH + NV*DH)        // V*DH bf16 (U = Xh@W^T)
#define OFF_YB   (OFF_UB + NV*DH/2)     // E*DH bf16
#define OFF_NCNT (OFF_YB + NE*DH/2)     // V ints  (written directly, no atomics)
#define OFF_ECNT (OFF_NCNT + NV)         // E ints  (dense, written by colscan)
#define OFF_EL   (OFF_ECNT + NE)         // E*CAP_E ints
#define OFF_NL   (OFF_EL + NE*CAP_E)     // V*CAP_V ints
#define OFF_XHB  (OFF_NL + NV*CAP_V)     // V*DH bf16

using bf16x8 = __attribute__((ext_vector_type(8))) short;
using f32x4  = __attribute__((ext_vector_type(4))) float;

__device__ inline unsigned short f2bf(float f) {   // round-to-nearest-even
    union { float f; unsigned u; } v; v.f = f;
    unsigned r = v.u + 0x7FFF + ((v.u >> 16) & 1);
    return (unsigned short)(r >> 16);
}
__device__ inline float b2f(unsigned short s) {
    union { unsigned u; float f; } v; v.u = ((unsigned)s) << 16; return v.f;
}

union ScanSmem {
    struct { short As[1024]; short Bs[8192]; } g;          // proj: 18 KB
    struct { int cnt[32]; int lbuf[32][CAP_E]; } c;        // colscan: 12.4 KB
};

// ---- one kernel, three concurrent block ranges (no cross-range deps):
//  [0, NPROJ):              proj GEMM  Xh = X @ Wp^T (BK=32)
//  [NPROJ, NPROJ+NCOL):     column scan -> edge_cnt/edge_list (LDS only, no global atomics)
//  [NPROJ+NCOL, +NROW):     row scan    -> node_cnt/node_list (prefix-sum, zero atomics)
__global__ __launch_bounds__(256) void scan_proj(const float* __restrict__ H,
                                                 const float* __restrict__ X,
                                                 const float* __restrict__ Wp,
                                                 float* __restrict__ Xh,
                                                 unsigned short* __restrict__ Xhb,
                                                 int* __restrict__ edge_cnt,
                                                 int* __restrict__ node_cnt,
                                                 int* __restrict__ edge_list,
                                                 int* __restrict__ node_list) {
    __shared__ ScanSmem sm;
    const int tid = threadIdx.x;

    if (blockIdx.x >= NPROJ + NCOL) {
        // ---------------- row scan: one WAVE per full row, NO atomics ----------------
        const int w = tid >> 6, lane = tid & 63;
        const int v = (blockIdx.x - NPROJ - NCOL) * 4 + w;
        const float4* H4 = (const float4*)(H + (size_t)v * NE);
        float4 h[16];
#pragma unroll
        for (int it = 0; it < 16; ++it) h[it] = H4[lane + 64 * it];   // 16 indep 1KB loads
        unsigned long long m = 0ull;
#pragma unroll
        for (int it = 0; it < 16; ++it) {
            float hv[4] = {h[it].x, h[it].y, h[it].z, h[it].w};
#pragma unroll
            for (int c = 0; c < 4; ++c)
                m |= (hv[c] != 0.0f ? 1ull : 0ull) << (it * 4 + c);
        }
        int n = __builtin_popcountll(m);
        int pre = n;
#pragma unroll
        for (int o = 1; o < 64; o <<= 1) {
            int t = __shfl_up(pre, o, 64);
            if (lane >= o) pre += t;
        }
        if (lane == 63) node_cnt[v] = pre;     // true degree, non-atomic
        int base = pre - n;
        unsigned long long mm = m;
        int k = 0;
        while (mm) {
            int j = __builtin_ctzll(mm); mm &= mm - 1;
            int ee = 256 * (j >> 2) + 4 * lane + (j & 3);
            int idx = base + k;
            if (idx < CAP_V) node_list[v * CAP_V + idx] = ee;
            ++k;
        }
        return;
    }
    if (blockIdx.x >= NPROJ) {
        // -------- column scan: block owns 32 edges (128B strip), all 8192 rows --------
        const int g = blockIdx.x - NPROJ;
        const int col0 = g * 32;
        if (tid < 32) sm.c.cnt[tid] = 0;
        __syncthreads();
#pragma unroll 1
        for (int it = 0; it < 16; ++it) {
            int r0 = tid + it * 512;
            int r1 = r0 + 256;
            const float4* p0 = (const float4*)(H + (size_t)r0 * NE + col0);
            const float4* p1 = (const float4*)(H + (size_t)r1 * NE + col0);
            float4 c0[8], c1[8];
#pragma unroll
            for (int q = 0; q < 8; ++q) c0[q] = p0[q];
#pragma unroll
            for (int q = 0; q < 8; ++q) c1[q] = p1[q];
            unsigned m0 = 0u, m1 = 0u;
#pragma unroll
            for (int q = 0; q < 8; ++q) {
                float a0[4] = {c0[q].x, c0[q].y, c0[q].z, c0[q].w};
                float a1[4] = {c1[q].x, c1[q].y, c1[q].z, c1[q].w};
#pragma unroll
                for (int c = 0; c < 4; ++c) {
                    m0 |= (a0[c] != 0.0f ? 1u : 0u) << (q * 4 + c);
                    m1 |= (a1[c] != 0.0f ? 1u : 0u) << (q * 4 + c);
                }
            }
            while (m0) {
                int j = __builtin_ctz(m0); m0 &= m0 - 1;
                int s = atomicAdd(&sm.c.cnt[j], 1);
                if (s < CAP_E) sm.c.lbuf[j][s] = r0;
            }
            while (m1) {
                int j = __builtin_ctz(m1); m1 &= m1 - 1;
                int s = atomicAdd(&sm.c.cnt[j], 1);
                if (s < CAP_E) sm.c.lbuf[j][s] = r1;
            }
        }
        __syncthreads();
        int j = tid >> 3, i0 = tid & 7;   // 8 threads per edge
        int e = col0 + j;
        int c = sm.c.cnt[j];
        if (i0 == 0) edge_cnt[e] = c;     // true count, non-atomic
        int cc = min(c, CAP_E);
        for (int i = i0; i < cc; i += 8) edge_list[e * CAP_E + i] = sm.c.lbuf[j][i];
        return;
    }
    // ---------------- proj GEMM path: BM=32, BN=256, BK=32, K=DIN ----------------
    short* As = sm.g.As;
    short* Bs = sm.g.Bs;
    const int K = DIN;
    const int lane = tid & 63;
    const int w    = tid >> 6;
    const int bm   = blockIdx.x * 32;
    const int swz  = lane ^ ((lane >> 3) & 6);
    float4 ar, br[8];
    ar = *(const float4*)(X + (size_t)(bm + (tid >> 3)) * K + ((tid & 7) << 2));
#pragma unroll
    for (int it = 0; it < 8; ++it) {
        int i = tid + it * 256;
        br[it] = *(const float4*)(Wp + (size_t)(i >> 3) * K + ((i & 7) << 2));
    }
    f32x4 acc[2][4];
#pragma unroll
    for (int mi = 0; mi < 2; ++mi)
#pragma unroll
        for (int ni = 0; ni < 4; ++ni) acc[mi][ni] = (f32x4){0.f, 0.f, 0.f, 0.f};
    for (int k0 = 0; k0 < K; k0 += 32) {
        __syncthreads();
        {
            int row = tid >> 3, kk = (tid & 7) << 2;
            int quad = kk >> 3, j = kk & 7;
            int ln = (row & 15) + (quad << 4);
            int pp = ln ^ ((ln >> 3) & 6);
            ushort4 u = {f2bf(ar.x), f2bf(ar.y), f2bf(ar.z), f2bf(ar.w)};
            *(ushort4*)&As[(row >> 4) * 512 + pp * 8 + j] = u;
        }
#pragma unroll
        for (int it = 0; it < 8; ++it) {
            int i = tid + it * 256;
            int row = i >> 3, kk = (i & 7) << 2;
            int quad = kk >> 3, j = kk & 7;
            int ln = (row & 15) + (quad << 4);
            int pp = ln ^ ((ln >> 3) & 6);
            float4 v = br[it];
            ushort4 u = {f2bf(v.x), f2bf(v.y), f2bf(v.z), f2bf(v.w)};
            *(ushort4*)&Bs[(row >> 4) * 512 + pp * 8 + j] = u;
        }
        __syncthreads();
        if (k0 + 32 < K) {
            int kn = k0 + 32;
            ar = *(const float4*)(X + (size_t)(bm + (tid >> 3)) * K + kn + ((tid & 7) << 2));
#pragma unroll
            for (int it = 0; it < 8; ++it) {
                int i = tid + it * 256;
                br[it] = *(const float4*)(Wp + (size_t)(i >> 3) * K + kn + ((i & 7) << 2));
            }
        }
        bf16x8 af[2], bfr[4];
        af[0] = *(const bf16x8*)&As[0 * 512 + swz * 8];
        af[1] = *(const bf16x8*)&As[1 * 512 + swz * 8];
#pragma unroll
        for (int ni = 0; ni < 4; ++ni)
            bfr[ni] = *(const bf16x8*)&Bs[(w * 4 + ni) * 512 + swz * 8];
#pragma unroll
        for (int mi = 0; mi < 2; ++mi)
#pragma unroll
            for (int ni = 0; ni < 4; ++ni)
                acc[mi][ni] = __builtin_amdgcn_mfma_f32_16x16x32_bf16(
                    af[mi], bfr[ni], acc[mi][ni], 0, 0, 0);
    }
    const int quad = lane >> 4, cl = lane & 15;
#pragma unroll
    for (int mi = 0; mi < 2; ++mi)
#pragma unroll
        for (int ni = 0; ni < 4; ++ni)
#pragma unroll
            for (int r = 0; r < 4; ++r) {
                float v = acc[mi][ni][r];
                size_t idx = (size_t)(bm + mi * 16 + quad * 4 + r) * DH + w * 64 + ni * 16 + cl;
                Xh[idx] = v;
                Xhb[idx] = f2bf(v);
            }
}

// ------- U = bf16(Xhb @ W^T): bf16 A (no conversion), K=256, BM=32 ----------
__global__ __launch_bounds__(256) void gemm_u(const unsigned short* __restrict__ A,
                                              const float* __restrict__ W,
                                              unsigned short* __restrict__ U) {
    const int K = DH;
    __shared__ short As[2048];
    __shared__ short Bs[16384];
    const int tid  = threadIdx.x;
    const int lane = tid & 63;
    const int w    = tid >> 6;
    const int bm   = blockIdx.x * 32;
    const int swz  = lane ^ ((lane >> 3) & 6);

    uint4 ar; float4 br[16];
    ar = *(const uint4*)(A + (size_t)(bm + (tid >> 3)) * K + ((tid & 7) << 3));
#pragma unroll
    for (int it = 0; it < 16; ++it) {
        int i = tid + it * 256;
        br[it] = *(const float4*)(W + (size_t)(i >> 4) * K + ((i & 15) << 2));
    }
    f32x4 acc[2][4];
#pragma unroll
    for (int mi = 0; mi < 2; ++mi)
#pragma unroll
        for (int ni = 0; ni < 4; ++ni) acc[mi][ni] = (f32x4){0.f, 0.f, 0.f, 0.f};

    for (int k0 = 0; k0 < K; k0 += 64) {
        __syncthreads();
        {   // A: 32x64 bf16, one uint4 (8 bf16) per thread
            int row = tid >> 3, kq = tid & 7;
            int kc = kq >> 2, quad = kq & 3;
            int ln = (row & 15) + (quad << 4);
            int pp = ln ^ ((ln >> 3) & 6);
            *(uint4*)&As[((row >> 4) * 2 + kc) * 512 + pp * 8] = ar;
        }
#pragma unroll
        for (int it = 0; it < 16; ++it) {   // B: 256x64 fp32 -> bf16
            int i = tid + it * 256;
            int row = i >> 4, kk = (i & 15) << 2;
            int kc = kk >> 5, quad = (kk >> 3) & 3, j = kk & 7;
            int ln = (row & 15) + (quad << 4);
            int pp = ln ^ ((ln >> 3) & 6);
            float4 v = br[it];
            ushort4 u = {f2bf(v.x), f2bf(v.y), f2bf(v.z), f2bf(v.w)};
            *(ushort4*)&Bs[((row >> 4) * 2 + kc) * 512 + pp * 8 + j] = u;
        }
        __syncthreads();
        if (k0 + 64 < K) {
            int kn = k0 + 64;
            ar = *(const uint4*)(A + (size_t)(bm + (tid >> 3)) * K + kn + ((tid & 7) << 3));
#pragma unroll
            for (int it = 0; it < 16; ++it) {
                int i = tid + it * 256;
                br[it] = *(const float4*)(W + (size_t)(i >> 4) * K + kn + ((i & 15) << 2));
            }
        }
#pragma unroll
        for (int kc = 0; kc < 2; ++kc) {
            bf16x8 af[2], bfr[4];
            af[0] = *(const bf16x8*)&As[(0 * 2 + kc) * 512 + swz * 8];
            af[1] = *(const bf16x8*)&As[(1 * 2 + kc) * 512 + swz * 8];
#pragma unroll
            for (int ni = 0; ni < 4; ++ni)
                bfr[ni] = *(const bf16x8*)&Bs[((w * 4 + ni) * 2 + kc) * 512 + swz * 8];
#pragma unroll
            for (int mi = 0; mi < 2; ++mi)
#pragma unroll
                for (int ni = 0; ni < 4; ++ni)
                    acc[mi][ni] = __builtin_amdgcn_mfma_f32_16x16x32_bf16(
                        af[mi], bfr[ni], acc[mi][ni], 0, 0, 0);
        }
    }
    const int quad = lane >> 4, cl = lane & 15;
#pragma unroll
    for (int mi = 0; mi < 2; ++mi)
#pragma unroll
        for (int ni = 0; ni < 4; ++ni)
#pragma unroll
            for (int r = 0; r < 4; ++r)
                U[(size_t)(bm + mi * 16 + quad * 4 + r) * DH + w * 64 + ni * 16 + cl]
                    = f2bf(acc[mi][ni][r]);
}

// ---- Yb[e,:] = bf16( rsqrt(de) * sum_{v in e} rsqrt(dv) * Ub[v,:] ) ----
__global__ __launch_bounds__(64) void edge_gather(const unsigned short* __restrict__ Ub,
                                                  const int* __restrict__ edge_cnt,
                                                  const int* __restrict__ edge_list,
                                                  const int* __restrict__ node_cnt,
                                                  unsigned short* __restrict__ Yb) {
    int e = blockIdx.x;
    int tid = threadIdx.x;
    __shared__ int   lv[CAP_E];
    __shared__ float lc[CAP_E];
    int tc = edge_cnt[e];
    int cnt = min(tc, CAP_E);
    for (int j = tid; j < cnt; j += 64) {
        int v = edge_list[e * CAP_E + j];
        lv[j] = v * (DH / 4);
        lc[j] = rsqrtf((float)node_cnt[v]);
    }
    __syncthreads();
    const ushort4* X4 = (const ushort4*)Ub;
    float4 a[8];
#pragma unroll
    for (int u = 0; u < 8; ++u) a[u] = (float4){0.f, 0.f, 0.f, 0.f};
    int i = 0;
    for (; i + 8 <= cnt; i += 8) {
#pragma unroll
        for (int u = 0; u < 8; ++u) {
            ushort4 h = X4[lv[i + u] + tid]; float c = lc[i + u];
            a[u].x = fmaf(c, b2f(h.x), a[u].x); a[u].y = fmaf(c, b2f(h.y), a[u].y);
            a[u].z = fmaf(c, b2f(h.z), a[u].z); a[u].w = fmaf(c, b2f(h.w), a[u].w);
        }
    }
    for (; i < cnt; ++i) {
        ushort4 h = X4[lv[i] + tid]; float c = lc[i];
        a[0].x = fmaf(c, b2f(h.x), a[0].x); a[0].y = fmaf(c, b2f(h.y), a[0].y);
        a[0].z = fmaf(c, b2f(h.z), a[0].z); a[0].w = fmaf(c, b2f(h.w), a[0].w);
    }
#pragma unroll
    for (int u = 4; u > 0; u >>= 1)
#pragma unroll
        for (int q = 0; q < u; ++q) {
            a[q].x += a[q + u].x; a[q].y += a[q + u].y;
            a[q].z += a[q + u].z; a[q].w += a[q + u].w;
        }
    float de = tc > 0 ? rsqrtf((float)tc) : 0.f;
    ushort4 o = {f2bf(de * a[0].x), f2bf(de * a[0].y),
                 f2bf(de * a[0].z), f2bf(de * a[0].w)};
    ((ushort4*)Yb)[e * (DH / 4) + tid] = o;
}

// ---- node gather + relu + residual + LayerNorm, one wave per row ----
__global__ __launch_bounds__(64) void node_ln(const unsigned short* __restrict__ Yb,
                                              const int* __restrict__ node_cnt,
                                              const int* __restrict__ node_list,
                                              const int* __restrict__ edge_cnt,
                                              float* __restrict__ Xh,
                                              unsigned short* __restrict__ Xhb,
                                              const float* __restrict__ g,
                                              const float* __restrict__ b) {
    int v = blockIdx.x;
    int tid = threadIdx.x;
    __shared__ int   le[CAP_V];
    __shared__ float lc[CAP_V];
    int tc = node_cnt[v];
    int cnt = min(tc, CAP_V);
    if (tid < cnt) {
        int e = node_list[v * CAP_V + tid];
        le[tid] = e * (DH / 4);
        lc[tid] = rsqrtf((float)edge_cnt[e]);
    }
    __syncthreads();
    const ushort4* Y4 = (const ushort4*)Yb;
    float4 a[8];
#pragma unroll
    for (int u = 0; u < 8; ++u) a[u] = (float4){0.f, 0.f, 0.f, 0.f};
    int i = 0;
    for (; i + 8 <= cnt; i += 8) {
#pragma unroll
        for (int u = 0; u < 8; ++u) {
            ushort4 h = Y4[le[i + u] + tid]; float c = lc[i + u];
            a[u].x = fmaf(c, b2f(h.x), a[u].x); a[u].y = fmaf(c, b2f(h.y), a[u].y);
            a[u].z = fmaf(c, b2f(h.z), a[u].z); a[u].w = fmaf(c, b2f(h.w), a[u].w);
        }
    }
    for (; i < cnt; ++i) {
        ushort4 h = Y4[le[i] + tid]; float c = lc[i];
        a[0].x = fmaf(c, b2f(h.x), a[0].x); a[0].y = fmaf(c, b2f(h.y), a[0].y);
        a[0].z = fmaf(c, b2f(h.z), a[0].z); a[0].w = fmaf(c, b2f(h.w), a[0].w);
    }
#pragma unroll
    for (int u = 4; u > 0; u >>= 1)
#pragma unroll
        for (int q = 0; q < u; ++q) {
            a[q].x += a[q + u].x; a[q].y += a[q + u].y;
            a[q].z += a[q + u].z; a[q].w += a[q + u].w;
        }
    float dv = tc > 0 ? rsqrtf((float)tc) : 0.f;
    float4 xr = ((const float4*)Xh)[v * (DH / 4) + tid];
    float x0 = xr.x + fmaxf(dv * a[0].x, 0.f);
    float x1 = xr.y + fmaxf(dv * a[0].y, 0.f);
    float x2 = xr.z + fmaxf(dv * a[0].z, 0.f);
    float x3 = xr.w + fmaxf(dv * a[0].w, 0.f);
    float s = (x0 + x1) + (x2 + x3);
    float q = fmaf(x0, x0, fmaf(x1, x1, fmaf(x2, x2, x3 * x3)));
#pragma unroll
    for (int o = 1; o < 64; o <<= 1) {
        s += __shfl_xor(s, o, 64);
        q += __shfl_xor(q, o, 64);
    }
    float m = s * (1.0f / DH);
    float var = q * (1.0f / DH) - m * m;
    float rstd = rsqrtf(var + 1e-5f);
    float4 g4 = ((const float4*)g)[tid];
    float4 b4 = ((const float4*)b)[tid];
    float4 o;
    o.x = (x0 - m) * rstd * g4.x + b4.x;
    o.y = (x1 - m) * rstd * g4.y + b4.y;
    o.z = (x2 - m) * rstd * g4.z + b4.z;
    o.w = (x3 - m) * rstd * g4.w + b4.w;
    ((float4*)Xh)[v * (DH / 4) + tid] = o;
    ushort4 ob = {f2bf(o.x), f2bf(o.y), f2bf(o.z), f2bf(o.w)};
    ((ushort4*)Xhb)[v * (DH / 4) + tid] = ob;
}

// ------- fused mean-pool + classifier + softmax (64 thr, bf16 src) -------
__global__ __launch_bounds__(64) void pool_classify(const unsigned short* __restrict__ Xhb,
                                                    const int* __restrict__ edge_cnt,
                                                    const int* __restrict__ edge_list,
                                                    const float* __restrict__ Wc,
                                                    const float* __restrict__ bc,
                                                    float* __restrict__ out) {
    int e = blockIdx.x;
    int tid = threadIdx.x;
    __shared__ int lv[CAP_E];
    int tc = edge_cnt[e];
    int cnt = min(tc, CAP_E);
    for (int j = tid; j < cnt; j += 64) lv[j] = edge_list[e * CAP_E + j] * (DH / 4);
    __syncthreads();
    const ushort4* X4 = (const ushort4*)Xhb;
    float4 a[8];
#pragma unroll
    for (int u = 0; u < 8; ++u) a[u] = (float4){0, 0, 0, 0};
    int i = 0;
    for (; i + 8 <= cnt; i += 8) {
#pragma unroll
        for (int u = 0; u < 8; ++u) {
            ushort4 h = X4[lv[i + u] + tid];
            a[u].x += b2f(h.x); a[u].y += b2f(h.y);
            a[u].z += b2f(h.z); a[u].w += b2f(h.w);
        }
    }
    for (; i < cnt; ++i) {
        ushort4 h = X4[lv[i] + tid];
        a[0].x += b2f(h.x); a[0].y += b2f(h.y);
        a[0].z += b2f(h.z); a[0].w += b2f(h.w);
    }
#pragma unroll
    for (int u = 4; u > 0; u >>= 1)
#pragma unroll
        for (int q = 0; q < u; ++q) {
            a[q].x += a[q + u].x; a[q].y += a[q + u].y;
            a[q].z += a[q + u].z; a[q].w += a[q + u].w;
        }
    float inv = tc > 0 ? 1.0f / (float)tc : 1.0f;
    float4 val = {a[0].x * inv, a[0].y * inv, a[0].z * inv, a[0].w * inv};
    const float4* W4 = (const float4*)Wc;
    float4 w0 = W4[tid], w1 = W4[64 + tid];
    float p0 = val.x * w0.x + val.y * w0.y + val.z * w0.z + val.w * w0.w;
    float p1 = val.x * w1.x + val.y * w1.y + val.z * w1.z + val.w * w1.w;
#pragma unroll
    for (int o = 32; o > 0; o >>= 1) {
        p0 += __shfl_down(p0, o, 64);
        p1 += __shfl_down(p1, o, 64);
    }
    if (tid == 0) {
        float l0 = p0 + bc[0], l1 = p1 + bc[1];
        float mx = fmaxf(l0, l1);
        float e0 = expf(l0 - mx), e1 = expf(l1 - mx);
        float s = 1.0f / (e0 + e1);
        out[e * 2 + 0] = e0 * s;
        out[e * 2 + 1] = e1 * s;
    }
}

extern "C" void kernel_launch(void* const* d_in, const int* in_sizes, int n_in,
                              void* d_out, int out_size, void* d_ws, size_t ws_size,
                              hipStream_t stream) {
    const float* X  = (const float*)d_in[0];
    const float* H  = (const float*)d_in[1];
    const float* Wp = (const float*)d_in[2];
    const float* W0 = (const float*)d_in[3];
    const float* W1 = (const float*)d_in[4];
    const float* g0 = (const float*)d_in[5];
    const float* b0 = (const float*)d_in[6];
    const float* g1 = (const float*)d_in[7];
    const float* b1 = (const float*)d_in[8];
    const float* Wc = (const float*)d_in[9];
    const float* bc = (const float*)d_in[10];
    float* out = (float*)d_out;

    float* ws = (float*)d_ws;
    float* Xh  = ws + OFF_XH;
    unsigned short* Ub  = (unsigned short*)(ws + OFF_UB);
    unsigned short* Yb  = (unsigned short*)(ws + OFF_YB);
    int* node_cnt  = (int*)(ws + OFF_NCNT);
    int* edge_cnt  = (int*)(ws + OFF_ECNT);
    int* edge_list = (int*)(ws + OFF_EL);
    int* node_list = (int*)(ws + OFF_NL);
    unsigned short* Xhb = (unsigned short*)(ws + OFF_XHB);

    // no memset needed: all counters are written non-atomically by the scan
    scan_proj<<<NPROJ + NCOL + NROW, 256, 0, stream>>>(H, X, Wp, Xh, Xhb,
                                                       edge_cnt, node_cnt,
                                                       edge_list, node_list);

    const float* Ws[2] = {W0, W1};
    const float* gs[2] = {g0, g1};
    const float* bs[2] = {b0, b1};
    for (int l = 0; l < 2; ++l) {
        gemm_u<<<NV / 32, 256, 0, stream>>>(Xhb, Ws[l], Ub);
        edge_gather<<<NE, 64, 0, stream>>>(Ub, edge_cnt, edge_list, node_cnt, Yb);
        node_ln<<<NV, 64, 0, stream>>>(Yb, node_cnt, node_list, edge_cnt,
                                       Xh, Xhb, gs[l], bs[l]);
    }

    pool_classify<<<NE, 64, 0, stream>>>(Xhb, edge_cnt, edge_list, Wc, bc, out);
}